// Round 5
// baseline (136.663 us; speedup 1.0000x reference)
//
#include <hip/hip_runtime.h>

// Voxel pooling v6: conflict-free bucket stores + split kernels for visibility.
// v5 post-mortem: scan ~40us / acc ~38us, both ~4x their traffic floors. Cause:
// lockstep LDS bank conflicts on bucket stores. stage[bin*16+idx] -> bank =
// (2*idx)%32 (bin drops out!), and idx values are clustered across lanes at any
// instant (lists fill in lockstep) -> 16-32-way ds_write_b64 conflicts. Same in
// acc: list[vl*56+idx] -> bank = (16vl+2idx)%32, 16vl%32 in {0,16} -> ~4 banks.
// Fixes: scan stores slot-swizzled by bin ((idx+bin)&15 -> bank spread by the
// random per-lane bin); acc uses VCAP=57 (18*vl%32 covers all 16 even offsets).
// Plus: 8 hoisted LDS atomics (ILP), wave-aggregated spillcnt atomic, 8-deep
// phase-2 chains, pre split into scan_kernel + tr_kernel.

namespace {
constexpr int NVX = 128, NVY = 128, C = 80;
constexpr int B = 2, N = 6, D = 112, H = 16, W = 44;
constexpr int HW    = H * W;             // 704
constexpr int BN    = B * N;             // 12
constexpr int DHW   = D * HW;            // 78848
constexpr int NDHW  = N * DHW;           // 473088 (points per batch)
constexpr int TOTAL = B * NDHW;          // 946176
constexpr int NVOX  = B * NVY * NVX;     // 32768

constexpr int NBIN  = 256;               // bin = v & 255
constexpr int VPB   = NVOX / NBIN;       // 128 voxels per bin (vl = v>>8)
constexpr int SLOT  = 16;                // slice stride in int2 (128B)
constexpr int CAP   = 15;                // 15 data slots + 1 count slot
constexpr int PTS_PER_BLK = 2048;
constexpr int SCAN_BLOCKS = TOTAL / PTS_PER_BLK;       // 462
constexpr int TR_BLOCKS   = BN * (C / 16) * (HW / 64); // 660
constexpr int SPILLCAP = 65536;

constexpr int VCAP = 57;                 // odd*2=114, 114%32=18, gcd(18,32)=2:
                                         // bucket-store banks spread (see above)
}

// ---- 1a. scan: LDS-bin 2048 pts/block, stream full-line slices to staging ----
__global__ __launch_bounds__(256) void scan_kernel(
    const int*   __restrict__ geom, const float* __restrict__ depth,
    int2* __restrict__ staging, int* __restrict__ spillcnt,
    int2* __restrict__ spill)
{
    __shared__ int2 stage[NBIN * SLOT];   // 32 KB
    __shared__ int  bcnt[NBIN];           // 1 KB

    const int t = threadIdx.x;
    const int lane = t & 63;
    bcnt[t] = 0;                          // NBIN == blockDim.x == 256
    __syncthreads();

    const int p0 = blockIdx.x * PTS_PER_BLK + t * 8;
    const int4* g4 = (const int4*)(geom + (size_t)3 * p0);  // 96B, aligned
    const int4 q0 = g4[0], q1 = g4[1], q2 = g4[2];
    const int4 q3 = g4[3], q4 = g4[4], q5 = g4[5];
    const float4 d0 = *(const float4*)(depth + p0);
    const float4 d1 = *(const float4*)(depth + p0 + 4);
    const int xs[8] = {q0.x, q0.w, q1.z, q2.y, q3.x, q3.w, q4.z, q5.y};
    const int ys[8] = {q0.y, q1.x, q1.w, q2.z, q3.y, q4.x, q4.w, q5.z};
    const int db[8] = {__float_as_int(d0.x), __float_as_int(d0.y),
                       __float_as_int(d0.z), __float_as_int(d0.w),
                       __float_as_int(d1.x), __float_as_int(d1.y),
                       __float_as_int(d1.z), __float_as_int(d1.w)};

    int bins[8], keys[8], idxv[8];
    #pragma unroll
    for (int u = 0; u < 8; ++u) {
        const int x = xs[u], y = ys[u];
        const bool ok = (unsigned)x < (unsigned)NVX && (unsigned)y < (unsigned)NVY;
        const int p   = p0 + u;
        const int b   = (p >= NDHW) ? 1 : 0;          // B == 2
        const int v   = (b * NVY + y) * NVX + x;
        const int bn  = (unsigned)p / (unsigned)DHW;
        const int hw  = (unsigned)p % (unsigned)HW;
        bins[u] = v & 255;
        keys[u] = (v << 14) | (bn * HW + hw);         // v:15b | row:14b
        idxv[u] = ok ? -1 : -2;                       // -2 = skip entirely
    }
    #pragma unroll
    for (int u = 0; u < 8; ++u)                       // 8 atomics in flight
        if (idxv[u] == -1) idxv[u] = atomicAdd(&bcnt[bins[u]], 1);
    #pragma unroll
    for (int u = 0; u < 8; ++u)                       // swizzled slot: bank =
        if ((unsigned)idxv[u] < (unsigned)CAP)        // (2idx+2bin)%32, spread
            stage[bins[u] * SLOT + ((idxv[u] + bins[u]) & 15)] =
                make_int2(keys[u], db[u]);
    #pragma unroll
    for (int u = 0; u < 8; ++u) {                     // wave-aggregated spill
        const bool sp = (idxv[u] >= CAP);
        const unsigned long long m = __ballot(sp);
        if (m) {
            const int leader = (int)__ffsll((unsigned long long)m) - 1;
            int base = 0;
            if (lane == leader) base = atomicAdd(spillcnt, (int)__popcll(m));
            base = __shfl(base, leader);
            if (sp) {
                const int off = base + (int)__popcll(m & ((1ull << lane) - 1ull));
                if (off < SPILLCAP) spill[off] = make_int2(keys[u], db[u]);
            }
        }
    }
    __syncthreads();
    stage[t * SLOT + ((t + CAP) & 15)].x = bcnt[t];   // count at logical slot 15
    __syncthreads();

    // stream out: 2048 int4; every global write a full 64B line
    const int4* src = (const int4*)stage;
    int4* dst = (int4*)staging;
    #pragma unroll
    for (int k = 0; k < 8; ++k) {
        const int i = k * 256 + t;            // 0..2047
        const int sl = i >> 3, part = i & 7;  // 8 int4 per slice
        dst[((size_t)sl * SCAN_BLOCKS + blockIdx.x) * 8 + part] = src[i];
    }
}

// ---- 1b. transpose ctx (bn, c, hw) -> ctx_t (bn*HW + hw, c) ----
__global__ __launch_bounds__(256) void tr_kernel(
    const float* __restrict__ ctx, float* __restrict__ ctx_t)
{
    __shared__ float tile[16 * 68];
    const int tb  = blockIdx.x;
    const int bn  = tb / 55;
    const int rem = tb % 55;
    const int c0  = (rem / 11) * 16;
    const int hw0 = (rem % 11) * 64;
    const int t = threadIdx.x;
    const int cl = t >> 6, hwl = t & 63;
    #pragma unroll
    for (int r = 0; r < 4; ++r) {
        const int c = r * 4 + cl;
        tile[c * 68 + hwl] = ctx[(size_t)(bn * C + c0 + c) * HW + hw0 + hwl];
    }
    __syncthreads();
    const int cr = t & 15, hwr = t >> 4;
    #pragma unroll
    for (int r = 0; r < 4; ++r) {
        const int hw = r * 16 + hwr;
        ctx_t[(size_t)(bn * HW + hw0 + hw) * C + c0 + cr] = tile[cr * 68 + hw];
    }
}

// ---- 2. acc: bucket into per-voxel LDS lists, then register-accumulate ----
__global__ __launch_bounds__(1024) void acc_kernel(
    const int2* __restrict__ staging, const float* __restrict__ ctx_t,
    float* __restrict__ out, int* __restrict__ spillcnt,
    int2* __restrict__ spill)
{
    __shared__ int2 list[VPB * VCAP];   // 58368 B
    __shared__ int  vcnt[VPB];          //   512 B

    const int bin  = blockIdx.x;
    const int t    = threadIdx.x;
    const int wave = t >> 6, lane = t & 63;

    if (t < VPB) vcnt[t] = 0;
    __syncthreads();

    // ---- phase 1: bucket. 4 slices per 64-lane chunk, coalesced 512B reads.
    const int sub = lane >> 4, slot = lane & 15;
    const int cslot   = (bin + CAP) & 15;        // physical count slot
    const int logical = (slot - bin) & 15;       // un-swizzle data slots
    for (int c = wave; c < (SCAN_BLOCKS + 3) / 4; c += 16) {
        const int s = c * 4 + sub;
        int2 e = make_int2(0, 0);
        if (s < SCAN_BLOCKS)
            e = staging[((size_t)bin * SCAN_BLOCKS + s) * SLOT + slot];
        int cnt = __shfl(e.x, (lane & 48) | cslot);
        cnt = cnt < CAP ? cnt : CAP;
        if (s < SCAN_BLOCKS && logical < cnt) {
            const int vl  = e.x >> 22;        // key = v<<14|row, v>>8 = vl
            const int idx = atomicAdd(&vcnt[vl], 1);
            if (idx < VCAP) {
                list[vl * VCAP + idx] = e;    // VCAP=57: banks spread by vl
            } else {
                int sp = atomicAdd(spillcnt, 1);
                if (sp < SPILLCAP) spill[sp] = e;
            }
        }
    }
    __syncthreads();

    // ---- phase 2: one wave per voxel, register accumulation, no atomics.
    const int off2 = 64 + (lane & 15);        // channels 64..79
    for (int vv = 0; vv < VPB / 16; ++vv) {   // 8 voxels per wave
        const int vl = wave * (VPB / 16) + vv;
        int n = vcnt[vl];
        n = n < VCAP ? n : VCAP;
        const int2* lp = list + vl * VCAP;

        float a0 = 0.f, a1 = 0.f, a2 = 0.f, a3 = 0.f;
        float a4 = 0.f, a5 = 0.f, a6 = 0.f, a7 = 0.f;
        float b0 = 0.f, b1 = 0.f, b2 = 0.f, b3 = 0.f;
        float b4 = 0.f, b5 = 0.f, b6 = 0.f, b7 = 0.f;
        int j = 0;
        for (; j + 8 <= n; j += 8) {          // 8 chains, 16 L2 loads in flight
            const int2 e0 = lp[j],     e1 = lp[j + 1], e2 = lp[j + 2], e3 = lp[j + 3];
            const int2 e4 = lp[j + 4], e5 = lp[j + 5], e6 = lp[j + 6], e7 = lp[j + 7];
            const float* c0 = ctx_t + (size_t)(e0.x & 16383) * C;
            const float* c1 = ctx_t + (size_t)(e1.x & 16383) * C;
            const float* c2 = ctx_t + (size_t)(e2.x & 16383) * C;
            const float* c3 = ctx_t + (size_t)(e3.x & 16383) * C;
            const float* c4 = ctx_t + (size_t)(e4.x & 16383) * C;
            const float* c5 = ctx_t + (size_t)(e5.x & 16383) * C;
            const float* c6 = ctx_t + (size_t)(e6.x & 16383) * C;
            const float* c7 = ctx_t + (size_t)(e7.x & 16383) * C;
            const float f0 = c0[lane], f1 = c1[lane], f2 = c2[lane], f3 = c3[lane];
            const float f4 = c4[lane], f5 = c5[lane], f6 = c6[lane], f7 = c7[lane];
            const float g0 = c0[off2], g1 = c1[off2], g2 = c2[off2], g3 = c3[off2];
            const float g4_ = c4[off2], g5 = c5[off2], g6 = c6[off2], g7 = c7[off2];
            const float w0 = __int_as_float(e0.y), w1 = __int_as_float(e1.y);
            const float w2 = __int_as_float(e2.y), w3 = __int_as_float(e3.y);
            const float w4 = __int_as_float(e4.y), w5 = __int_as_float(e5.y);
            const float w6 = __int_as_float(e6.y), w7 = __int_as_float(e7.y);
            a0 += w0 * f0; a1 += w1 * f1; a2 += w2 * f2; a3 += w3 * f3;
            a4 += w4 * f4; a5 += w5 * f5; a6 += w6 * f6; a7 += w7 * f7;
            b0 += w0 * g0; b1 += w1 * g1; b2 += w2 * g2; b3 += w3 * g3;
            b4 += w4 * g4_; b5 += w5 * g5; b6 += w6 * g6; b7 += w7 * g7;
        }
        for (; j + 4 <= n; j += 4) {
            const int2 e0 = lp[j], e1 = lp[j + 1], e2 = lp[j + 2], e3 = lp[j + 3];
            const float* c0 = ctx_t + (size_t)(e0.x & 16383) * C;
            const float* c1 = ctx_t + (size_t)(e1.x & 16383) * C;
            const float* c2 = ctx_t + (size_t)(e2.x & 16383) * C;
            const float* c3 = ctx_t + (size_t)(e3.x & 16383) * C;
            const float f0 = c0[lane], f1 = c1[lane], f2 = c2[lane], f3 = c3[lane];
            const float g0 = c0[off2], g1 = c1[off2], g2 = c2[off2], g3 = c3[off2];
            const float w0 = __int_as_float(e0.y), w1 = __int_as_float(e1.y);
            const float w2 = __int_as_float(e2.y), w3 = __int_as_float(e3.y);
            a0 += w0 * f0; a1 += w1 * f1; a2 += w2 * f2; a3 += w3 * f3;
            b0 += w0 * g0; b1 += w1 * g1; b2 += w2 * g2; b3 += w3 * g3;
        }
        for (; j < n; ++j) {
            const int2 e = lp[j];
            const float* c = ctx_t + (size_t)(e.x & 16383) * C;
            const float w = __int_as_float(e.y);
            a0 += w * c[lane];
            b0 += w * c[off2];
        }
        const float av = ((a0 + a1) + (a2 + a3)) + ((a4 + a5) + (a6 + a7));
        const float bv = ((b0 + b1) + (b2 + b3)) + ((b4 + b5) + (b6 + b7));
        float* o = out + (size_t)((vl << 8) | bin) * C;   // v = vl<<8 | bin
        o[lane] = av;
        if (lane < 16) o[64 + lane] = bv;
    }
}

// ---- 3. spill fixup (exact; ~1.2k entries expected) ----
__global__ __launch_bounds__(256) void spill_kernel(
    const int* __restrict__ spillcnt, const int2* __restrict__ spill,
    const float* __restrict__ ctx_t, float* __restrict__ out)
{
    const int nwaves = gridDim.x * 4;
    const int wave   = blockIdx.x * 4 + (threadIdx.x >> 6);
    const int lane   = threadIdx.x & 63;
    int cnt = *spillcnt;
    if (cnt > SPILLCAP) cnt = SPILLCAP;
    for (int i = wave; i < cnt; i += nwaves) {
        const int2 e = spill[i];
        const int v   = e.x >> 14;          // key < 2^29, positive
        const int row = e.x & 16383;
        const float dep = __int_as_float(e.y);
        const float* c = ctx_t + (size_t)row * C;
        float* o = out + (size_t)v * C;
        unsafeAtomicAdd(o + lane, dep * c[lane]);
        if (lane < C - 64) unsafeAtomicAdd(o + 64 + lane, dep * c[64 + lane]);
    }
}

extern "C" void kernel_launch(void* const* d_in, const int* in_sizes, int n_in,
                              void* d_out, int out_size, void* d_ws, size_t ws_size,
                              hipStream_t stream) {
    const int*   geom  = (const int*)d_in[0];
    const float* depth = (const float*)d_in[1];
    const float* ctx   = (const float*)d_in[2];
    float*       out   = (float*)d_out;

    // Workspace (~18.4 MB, all segments 256B-multiple):
    char* ws = (char*)d_ws;
    int2* staging  = (int2*)ws; ws += (size_t)SCAN_BLOCKS * NBIN * SLOT * 8; // 15,138,816
    int2* spill    = (int2*)ws; ws += (size_t)SPILLCAP * 8;                  // 524,288
    int*  spillcnt = (int*)ws;  ws += 256;
    float* ctx_t   = (float*)ws;                                             // 2,703,360

    hipMemsetAsync(spillcnt, 0, 256, stream);

    scan_kernel <<<dim3(SCAN_BLOCKS), dim3(256),  0, stream>>>(
                    geom, depth, staging, spillcnt, spill);
    tr_kernel   <<<dim3(TR_BLOCKS),   dim3(256),  0, stream>>>(ctx, ctx_t);
    acc_kernel  <<<dim3(NBIN),        dim3(1024), 0, stream>>>(
                    staging, ctx_t, out, spillcnt, spill);
    spill_kernel<<<dim3(64),          dim3(256),  0, stream>>>(spillcnt, spill, ctx_t, out);
}